// Round 5
// baseline (397.167 us; speedup 1.0000x reference)
//
#include <hip/hip_runtime.h>
#include <hip/hip_bf16.h>

typedef _Float16 half8 __attribute__((ext_vector_type(8)));
typedef _Float16 half4 __attribute__((ext_vector_type(4)));
typedef float float4v __attribute__((ext_vector_type(4)));

#define BATCH 32768
#define TT 30

#if __has_builtin(__builtin_amdgcn_exp2f)
#define FEXP2(x) __builtin_amdgcn_exp2f(x)
#else
#define FEXP2(x) __expf((x) * 0.6931471805599453f)
#endif
#if __has_builtin(__builtin_amdgcn_rcpf)
#define FRCP(x) __builtin_amdgcn_rcpf(x)
#else
#define FRCP(x) (1.0f / (x))
#endif

#define NLOG2E  -1.4426950408889634f
#define N2LOG2E -2.8853900817779268f

// ws offsets (floats). Gate weights/biases PRESCALED (-log2e; gate g -2log2e).
// 16x16x32 fragment layouts: A row=lane&15, k=(lane>>4)*8+j; B col=lane&15,
// same k; C/D col=lane&15, row=(lane>>4)*4+reg.
#define WFRAG_OFF 0        // f16[4 ug][4 gate][3 ks][64 lane][8] = 24576 halves
#define WCF_OFF   12288    // f16[2 role][2 ks][64 lane][8] = 2048 halves
#define BIASB_OFF 13312    // f32[256]  (b_ih + b_hh) * gate_scale
#define SXY_OFF   13568    // f32[16][3]   (Sx, Sy, bse)
#define CBIAS_OFF 13616    // f32[2][16]   (role0: bpos|0, role1: bx)
#define WCONF_OFF 13648    // f32[384]
#define BCONF_OFF 14032    // f32[6]
#define FLAG_IDX  14038    // int: 1 => inputs fp32, 0 => bf16
#define CONF_BASE (BATCH * 360)

__global__ void detect_kernel(const unsigned short* __restrict__ raw,
                              int* __restrict__ flag_out) {
    __shared__ int sflag[256];
    int local = 0;
    for (int i = threadIdx.x; i < 16384; i += 256) {
        unsigned short u = raw[i];
        if ((u & 0x7F80u) == 0x7F80u) local = 1;
    }
    sflag[threadIdx.x] = local;
    __syncthreads();
    if (threadIdx.x == 0) {
        int f = 0;
        for (int i = 0; i < 256; ++i) f |= sflag[i];
        flag_out[0] = f;
    }
}

__device__ __forceinline__ float ldin(const void* p, int i, int isf32) {
    return isf32 ? ((const float*)p)[i]
                 : (float)((const __hip_bfloat16*)p)[i];
}

__global__ void prep_kernel(const void* __restrict__ W_ih,
                            const void* __restrict__ W_hh,
                            const void* __restrict__ b_ih,
                            const void* __restrict__ b_hh,
                            const void* __restrict__ W_se,
                            const void* __restrict__ b_se,
                            const void* __restrict__ W_pos,
                            const void* __restrict__ b_pos,
                            const void* __restrict__ W_conf,
                            const void* __restrict__ b_conf,
                            float* __restrict__ ws)
{
    const int isf32 = ((const int*)(ws + FLAG_IDX))[0];
    int tid = blockIdx.x * blockDim.x + threadIdx.x;
    int stride = gridDim.x * blockDim.x;
    _Float16* wfh = (_Float16*)ws;

    // Gate-GEMM B fragments, 16x16x32 tiles, K padded to 96 (k>=80 -> 0).
    // u-group ug owns units [16ug,16ug+16); row = gate*64 + ug*16 + col.
    for (int idx = tid; idx < 24576; idx += stride) {
        int jj = idx & 7, r = idx >> 3;
        int lane = r & 63; r >>= 6;
        int ks = r % 3; r /= 3;
        int gate = r & 3; int ug = r >> 2;
        int col = lane & 15, akq = lane >> 4;
        int k = ks * 32 + akq * 8 + jj;
        int row = gate * 64 + ug * 16 + col;
        float v = 0.f;
        if (k < 16) v = ldin(W_ih, row * 16 + k, isf32);
        else if (k < 80) v = ldin(W_hh, row * 64 + (k - 16), isf32);
        v *= (gate == 2) ? N2LOG2E : NLOG2E;
        wfh[idx] = (_Float16)v;
    }
    // Fused C-GEMM fragments: role0 cols = Wpos (rel), role1 cols = M=Wse*Wpos (x).
    _Float16* wch = (_Float16*)(ws + WCF_OFF);
    for (int idx = tid; idx < 2048; idx += stride) {
        int jj = idx & 7, r = idx >> 3;
        int lane = r & 63; r >>= 6;
        int ks = r & 1, role = r >> 1;
        int col = lane & 15, akq = lane >> 4;
        int k = ks * 32 + akq * 8 + jj;   // 0..63 over h
        float v = 0.f;
        if (role == 0) {
            if (col < 12) v = ldin(W_pos, col * 64 + k, isf32);
        } else {
            float s = 0.f;
            for (int p = 0; p < 12; ++p)
                s += ldin(W_se, col * 12 + p, isf32) * ldin(W_pos, p * 64 + k, isf32);
            v = s;
        }
        wch[idx] = (_Float16)v;
    }
    for (int idx = tid; idx < 256; idx += stride) {
        int gate = idx >> 6;
        float scale = (gate == 2) ? N2LOG2E : NLOG2E;
        ws[BIASB_OFF + idx] = (ldin(b_ih, idx, isf32) + ldin(b_hh, idx, isf32)) * scale;
    }
    for (int idx = tid; idx < 16; idx += stride) {
        float sx = 0.f, sy = 0.f;
        for (int m = 0; m < 6; ++m) {
            sx += ldin(W_se, idx * 12 + 2 * m, isf32);
            sy += ldin(W_se, idx * 12 + 2 * m + 1, isf32);
        }
        ws[SXY_OFF + idx * 3 + 0] = sx;
        ws[SXY_OFF + idx * 3 + 1] = sy;
        ws[SXY_OFF + idx * 3 + 2] = ldin(b_se, idx, isf32);
    }
    for (int idx = tid; idx < 32; idx += stride) {
        int w = idx >> 4, cc = idx & 15;
        float v = 0.f;
        if (w == 0) {
            if (cc < 12) v = ldin(b_pos, cc, isf32);
        } else {
            float s = ldin(b_se, cc, isf32);
            for (int p = 0; p < 12; ++p)
                s += ldin(W_se, cc * 12 + p, isf32) * ldin(b_pos, p, isf32);
            v = s;
        }
        ws[CBIAS_OFF + idx] = v;
    }
    for (int idx = tid; idx < 384; idx += stride)
        ws[WCONF_OFF + idx] = ldin(W_conf, idx, isf32);
    for (int idx = tid; idx < 6; idx += stride)
        ws[BCONF_OFF + idx] = ldin(b_conf, idx, isf32);
}

// WAVE-AUTONOMOUS: block = 256 thr (4 waves), each wave owns 16 agents for
// the ENTIRE recurrence -- gate GEMM, activations, C-GEMM, pred/x/conf.
// All hazards are in-wave program-order LDS dependencies (DS ops from one
// wave execute in order), so the main loop has ZERO barriers; the block's
// waves (and the co-resident block's) slip freely against each other to
// keep the trans pipe fed.  Gate B-fragments (48 KB) are staged once into
// block-shared LDS; per-wave z strip: [16 agents][104 halves] =
// [x 0..15 | h 16..79 | zeros 80..95 | pad].  rel cols store straight to
// global (lane pairs are address-adjacent -> 8B coalescing).
__global__ __launch_bounds__(256, 2) void lstm_kernel(
    const void* __restrict__ traj_rel,
    const void* __restrict__ h0,
    const void* __restrict__ c0,
    const float* __restrict__ ws,
    float* __restrict__ out)
{
    __shared__ _Float16 wldsh[24576];      // gate B-frags (49152 B)
    __shared__ _Float16 zsh[4 * 16 * 104]; // per-wave z strips (13312 B)

    const int tid = threadIdx.x;
    const int lane = tid & 63;
    const int wid = __builtin_amdgcn_readfirstlane(tid >> 6);  // wave 0..3
    const int col16 = lane & 15;
    const int q4 = lane >> 4;            // 0..3
    const int base = blockIdx.x * 64;
    const int gbase = base + wid * 16;   // this wave's first agent
    const int isf32 = ((const int*)(ws + FLAG_IDX))[0];

    // ---- stage gate weight fragments into LDS (3072 float4 / 256 thr) ----
    {
        const float4* src = (const float4*)ws;
        float4* dst = (float4*)wldsh;
#pragma unroll
        for (int k = 0; k < 12; ++k)
            dst[k * 256 + tid] = src[k * 256 + tid];
    }

    _Float16* const zw = &zsh[wid * 1664];

    // ---- per-lane constants ----
    float bias16[16];
#pragma unroll
    for (int u = 0; u < 4; ++u)
#pragma unroll
        for (int g = 0; g < 4; ++g)
            bias16[u * 4 + g] = ws[BIASB_OFF + g * 64 + u * 16 + col16];
    half8 wfcR[2], wfcX[2];
    {
        const float4v* wcg = (const float4v*)(ws + WCF_OFF);
#pragma unroll
        for (int ks = 0; ks < 2; ++ks) {
            wfcR[ks] = __builtin_bit_cast(half8, wcg[ks * 64 + lane]);
            wfcX[ks] = __builtin_bit_cast(half8, wcg[(2 + ks) * 64 + lane]);
        }
    }
    const float cbr = ws[CBIAS_OFF + col16];
    const float cbx = ws[CBIAS_OFF + 16 + col16];

    // ---- c state: 16 cells/lane, cell (agent q4*4+i, unit u*16+col16) ----
    float c[16];
#pragma unroll
    for (int u = 0; u < 4; ++u)
#pragma unroll
        for (int i = 0; i < 4; ++i)
            c[u * 4 + i] = ldin(c0, (gbase + q4 * 4 + i) * 64 + u * 16 + col16, isf32);

    // ---- init z: h0, x0, zero-pad ----
    {
        int r = col16;   // agent r of this wave
        half8 ha, hb;
#pragma unroll
        for (int i = 0; i < 8; ++i)
            ha[i] = (_Float16)ldin(h0, (gbase + r) * 64 + q4 * 16 + i, isf32);
#pragma unroll
        for (int i = 0; i < 8; ++i)
            hb[i] = (_Float16)ldin(h0, (gbase + r) * 64 + q4 * 16 + 8 + i, isf32);
        *(half8*)&zw[r * 104 + 16 + q4 * 16] = ha;
        *(half8*)&zw[r * 104 + 16 + q4 * 16 + 8] = hb;
        float rx = ldin(traj_rel, 2 * (gbase + r), isf32);
        float ry = ldin(traj_rel, 2 * (gbase + r) + 1, isf32);
        half4 xs;
#pragma unroll
        for (int i = 0; i < 4; ++i) {
            int e = 4 * q4 + i;
            float x = fmaf(rx, ws[SXY_OFF + e * 3],
                      fmaf(ry, ws[SXY_OFF + e * 3 + 1], ws[SXY_OFF + e * 3 + 2]));
            xs[i] = (_Float16)(x > 0.f ? x : 0.01f * x);
        }
        *(half4*)&zw[r * 104 + 4 * q4] = xs;
        if (q4 == 0) {   // zero halves 80..103 (k-pad + stride pad)
            half8 zz = {};
            *(half8*)&zw[r * 104 + 80] = zz;
            *(half8*)&zw[r * 104 + 88] = zz;
            *(half8*)&zw[r * 104 + 96] = zz;
        }
    }
    __syncthreads();   // weights + z staged; ONLY barrier in the kernel

    const int aoffb = col16 * 104 + q4 * 8;   // A-frag base (k chunk)
    // pred store base: out[(agent)*360 + m*60 + t*2 + xy], p=col16=2m+xy
    float* const op0 = out + (size_t)(gbase + q4 * 4) * 360
                       + (col16 >> 1) * 60 + (col16 & 1);

    for (int t = 0; t < TT; ++t) {
        // ---- A-frags for gate GEMM (k = 0..95) ----
        half8 az0 = *(const half8*)&zw[aoffb];
        half8 az1 = *(const half8*)&zw[aoffb + 32];
        half8 az2 = *(const half8*)&zw[aoffb + 64];

        // ---- gates + activations per u-group (units u*16..u*16+16) ----
#pragma unroll
        for (int u = 0; u < 4; ++u) {
            float4v acc[4];
#pragma unroll
            for (int g = 0; g < 4; ++g) {
                float bv = bias16[u * 4 + g];
                acc[g][0] = bv; acc[g][1] = bv; acc[g][2] = bv; acc[g][3] = bv;
            }
#pragma unroll
            for (int g = 0; g < 4; ++g) {
                const int fb = ((u * 4 + g) * 3) * 512 + lane * 8;
                acc[g] = __builtin_amdgcn_mfma_f32_16x16x32_f16(
                    az0, *(const half8*)&wldsh[fb], acc[g], 0, 0, 0);
                acc[g] = __builtin_amdgcn_mfma_f32_16x16x32_f16(
                    az1, *(const half8*)&wldsh[fb + 512], acc[g], 0, 0, 0);
                acc[g] = __builtin_amdgcn_mfma_f32_16x16x32_f16(
                    az2, *(const half8*)&wldsh[fb + 1024], acc[g], 0, 0, 0);
            }
#pragma unroll
            for (int i = 0; i < 4; ++i) {
                float ei = FEXP2(acc[0][i]);
                float ef = FEXP2(acc[1][i]);
                float eg = FEXP2(acc[2][i]);
                float eo = FEXP2(acc[3][i]);
                float pp = (1.f + ei) * (1.f + eg);
                float qq = 1.f + ef;
                float cn = fmaf(c[u * 4 + i], pp, (1.f - eg) * qq) * FRCP(pp * qq);
                c[u * 4 + i] = cn;
                float ec = FEXP2(cn * N2LOG2E);
                float hn = (1.f - ec) * FRCP((1.f + eo) * (1.f + ec));
                zw[(q4 * 4 + i) * 104 + 16 + u * 16 + col16] = (_Float16)hn;
            }
        }

        // ---- C-GEMM: (rel | x) = h_new @ [Wpos | M]^T (in-wave h reuse) ----
        half8 ah0 = *(const half8*)&zw[aoffb + 16];
        half8 ah1 = *(const half8*)&zw[aoffb + 48];
        float4v rr, rx;
        rr[0] = cbr; rr[1] = cbr; rr[2] = cbr; rr[3] = cbr;
        rx[0] = cbx; rx[1] = cbx; rx[2] = cbx; rx[3] = cbx;
        rr = __builtin_amdgcn_mfma_f32_16x16x32_f16(ah0, wfcR[0], rr, 0, 0, 0);
        rr = __builtin_amdgcn_mfma_f32_16x16x32_f16(ah1, wfcR[1], rr, 0, 0, 0);
        rx = __builtin_amdgcn_mfma_f32_16x16x32_f16(ah0, wfcX[0], rx, 0, 0, 0);
        rx = __builtin_amdgcn_mfma_f32_16x16x32_f16(ah1, wfcX[1], rx, 0, 0, 0);

        if (col16 < 12) {   // pred -> global (lane pairs 2m/2m+1 adjacent)
#pragma unroll
            for (int i = 0; i < 4; ++i)
                op0[(size_t)i * 360 + t * 2] = rr[i];
        }
        if (t != TT - 1) {  // x = lrelu(.) back into z cols 0..15
#pragma unroll
            for (int i = 0; i < 4; ++i) {
                float xv = rx[i];
                xv = xv > 0.f ? xv : 0.01f * xv;
                zw[(q4 * 4 + i) * 104 + col16] = (_Float16)xv;
            }
        }
    }

    // ---- conf = softmax(h_30 @ Wconf^T + bconf), per wave, no barrier ----
    {
        int r = lane >> 2, qq = lane & 3;   // agent r, k-quarter qq
        float l[6];
#pragma unroll
        for (int md = 0; md < 6; ++md)
            l[md] = (qq == 0) ? ws[BCONF_OFF + md] : 0.f;
#pragma unroll
        for (int jj = 0; jj < 16; ++jj) {
            float hv = (float)zw[r * 104 + 16 + qq * 16 + jj];
#pragma unroll
            for (int md = 0; md < 6; ++md)
                l[md] = fmaf(hv, ws[WCONF_OFF + md * 64 + qq * 16 + jj], l[md]);
        }
#pragma unroll
        for (int md = 0; md < 6; ++md) {
            l[md] += __shfl_xor(l[md], 1);
            l[md] += __shfl_xor(l[md], 2);
        }
        if (qq == 0) {
            float mx = l[0];
#pragma unroll
            for (int md = 1; md < 6; ++md) mx = fmaxf(mx, l[md]);
            float ex[6], s = 0.f;
#pragma unroll
            for (int md = 0; md < 6; ++md) { ex[md] = __expf(l[md] - mx); s += ex[md]; }
            float inv = FRCP(s);
#pragma unroll
            for (int md = 0; md < 6; ++md)
                out[CONF_BASE + (size_t)(gbase + r) * 6 + md] = ex[md] * inv;
        }
    }
}

extern "C" void kernel_launch(void* const* d_in, const int* in_sizes, int n_in,
                              void* d_out, int out_size, void* d_ws, size_t ws_size,
                              hipStream_t stream) {
    const void* traj_rel = d_in[1];
    const void* h0   = d_in[2];
    const void* c0   = d_in[3];
    const void* W_ih = d_in[4];
    const void* W_hh = d_in[5];
    const void* b_ih = d_in[6];
    const void* b_hh = d_in[7];
    const void* W_se = d_in[8];
    const void* b_se = d_in[9];
    const void* W_pos  = d_in[10];
    const void* b_pos  = d_in[11];
    const void* W_conf = d_in[12];
    const void* b_conf = d_in[13];
    float* ws = (float*)d_ws;
    float* out = (float*)d_out;

    detect_kernel<<<1, 256, 0, stream>>>((const unsigned short*)W_hh,
                                         (int*)(ws + FLAG_IDX));
    prep_kernel<<<40, 256, 0, stream>>>(W_ih, W_hh, b_ih, b_hh, W_se, b_se,
                                        W_pos, b_pos, W_conf, b_conf, ws);
    lstm_kernel<<<BATCH / 64, 256, 0, stream>>>(traj_rel, h0, c0, ws, out);
}

// Round 6
// 205.260 us; speedup vs baseline: 1.9349x; 1.9349x over previous
//
#include <hip/hip_runtime.h>
#include <hip/hip_bf16.h>

typedef _Float16 half8 __attribute__((ext_vector_type(8)));
typedef _Float16 half4 __attribute__((ext_vector_type(4)));
typedef float float4v __attribute__((ext_vector_type(4)));

#define BATCH 32768
#define TT 30

#if __has_builtin(__builtin_amdgcn_exp2f)
#define FEXP2(x) __builtin_amdgcn_exp2f(x)
#else
#define FEXP2(x) __expf((x) * 0.6931471805599453f)
#endif
#if __has_builtin(__builtin_amdgcn_rcpf)
#define FRCP(x) __builtin_amdgcn_rcpf(x)
#else
#define FRCP(x) (1.0f / (x))
#endif

#define NLOG2E  -1.4426950408889634f
#define N2LOG2E -2.8853900817779268f

// ws offsets (floats). Gate weights/biases PRESCALED (-log2e; gate g -2log2e).
// 16x16x32 fragment layouts: A row=lane&15, k=(lane>>4)*8+j; B col=lane&15,
// same k; C/D col=lane&15, row=(lane>>4)*4+reg.
#define WFRAG_OFF 0        // f16[2 w][2 ug][4 gate][3 ks][64 lane][8] = 24576 halves
#define WCF_OFF   12288    // f16[2 role][2 ks][64 lane][8] = 2048 halves
#define BIASB_OFF 13312    // f32[256]  (b_ih + b_hh) * gate_scale
#define SXY_OFF   13568    // f32[16][3]   (Sx, Sy, bse)
#define CBIAS_OFF 13616    // f32[2][16]   (role0: bpos|0, role1: bx)
#define WCONF_OFF 13648    // f32[384]
#define BCONF_OFF 14032    // f32[6]
#define FLAG_IDX  14038    // int: 1 => inputs fp32, 0 => bf16
#define CONF_BASE (BATCH * 360)

__global__ void detect_kernel(const unsigned short* __restrict__ raw,
                              int* __restrict__ flag_out) {
    __shared__ int sflag[256];
    int local = 0;
    for (int i = threadIdx.x; i < 16384; i += 256) {
        unsigned short u = raw[i];
        if ((u & 0x7F80u) == 0x7F80u) local = 1;
    }
    sflag[threadIdx.x] = local;
    __syncthreads();
    if (threadIdx.x == 0) {
        int f = 0;
        for (int i = 0; i < 256; ++i) f |= sflag[i];
        flag_out[0] = f;
    }
}

__device__ __forceinline__ float ldin(const void* p, int i, int isf32) {
    return isf32 ? ((const float*)p)[i]
                 : (float)((const __hip_bfloat16*)p)[i];
}

__global__ void prep_kernel(const void* __restrict__ W_ih,
                            const void* __restrict__ W_hh,
                            const void* __restrict__ b_ih,
                            const void* __restrict__ b_hh,
                            const void* __restrict__ W_se,
                            const void* __restrict__ b_se,
                            const void* __restrict__ W_pos,
                            const void* __restrict__ b_pos,
                            const void* __restrict__ W_conf,
                            const void* __restrict__ b_conf,
                            float* __restrict__ ws)
{
    const int isf32 = ((const int*)(ws + FLAG_IDX))[0];
    int tid = blockIdx.x * blockDim.x + threadIdx.x;
    int stride = gridDim.x * blockDim.x;
    _Float16* wfh = (_Float16*)ws;

    // Gate-GEMM B fragments, 16x16x32 tiles, K padded to 96 (k>=80 -> 0).
    // Wave w owns units [32w,32w+32); tile (w,ug,gate):
    // row = gate*64 + w*32 + ug*16 + col.
    for (int idx = tid; idx < 24576; idx += stride) {
        int jj = idx & 7, r = idx >> 3;
        int lane = r & 63; r >>= 6;
        int ks = r % 3; r /= 3;
        int gate = r & 3; r >>= 2;
        int ug = r & 1; int w = r >> 1;
        int col = lane & 15, akq = lane >> 4;
        int k = ks * 32 + akq * 8 + jj;
        int row = gate * 64 + w * 32 + ug * 16 + col;
        float v = 0.f;
        if (k < 16) v = ldin(W_ih, row * 16 + k, isf32);
        else if (k < 80) v = ldin(W_hh, row * 64 + (k - 16), isf32);
        v *= (gate == 2) ? N2LOG2E : NLOG2E;
        wfh[idx] = (_Float16)v;
    }
    // Fused C-GEMM fragments: role0 cols = Wpos (rel), role1 cols = M=Wse*Wpos (x).
    _Float16* wch = (_Float16*)(ws + WCF_OFF);
    for (int idx = tid; idx < 2048; idx += stride) {
        int jj = idx & 7, r = idx >> 3;
        int lane = r & 63; r >>= 6;
        int ks = r & 1, role = r >> 1;
        int col = lane & 15, akq = lane >> 4;
        int k = ks * 32 + akq * 8 + jj;   // 0..63 over h
        float v = 0.f;
        if (role == 0) {
            if (col < 12) v = ldin(W_pos, col * 64 + k, isf32);
        } else {
            float s = 0.f;
            for (int p = 0; p < 12; ++p)
                s += ldin(W_se, col * 12 + p, isf32) * ldin(W_pos, p * 64 + k, isf32);
            v = s;
        }
        wch[idx] = (_Float16)v;
    }
    for (int idx = tid; idx < 256; idx += stride) {
        int gate = idx >> 6;
        float scale = (gate == 2) ? N2LOG2E : NLOG2E;
        ws[BIASB_OFF + idx] = (ldin(b_ih, idx, isf32) + ldin(b_hh, idx, isf32)) * scale;
    }
    for (int idx = tid; idx < 16; idx += stride) {
        float sx = 0.f, sy = 0.f;
        for (int m = 0; m < 6; ++m) {
            sx += ldin(W_se, idx * 12 + 2 * m, isf32);
            sy += ldin(W_se, idx * 12 + 2 * m + 1, isf32);
        }
        ws[SXY_OFF + idx * 3 + 0] = sx;
        ws[SXY_OFF + idx * 3 + 1] = sy;
        ws[SXY_OFF + idx * 3 + 2] = ldin(b_se, idx, isf32);
    }
    for (int idx = tid; idx < 32; idx += stride) {
        int w = idx >> 4, cc = idx & 15;
        float v = 0.f;
        if (w == 0) {
            if (cc < 12) v = ldin(b_pos, cc, isf32);
        } else {
            float s = ldin(b_se, cc, isf32);
            for (int p = 0; p < 12; ++p)
                s += ldin(W_se, cc * 12 + p, isf32) * ldin(b_pos, p, isf32);
            v = s;
        }
        ws[CBIAS_OFF + idx] = v;
    }
    for (int idx = tid; idx < 384; idx += stride)
        ws[WCONF_OFF + idx] = ldin(W_conf, idx, isf32);
    for (int idx = tid; idx < 6; idx += stride)
        ws[BCONF_OFF + idx] = ldin(b_conf, idx, isf32);
}

// 2-WAVE TEAMS: block = 128 thr = 1 team = 16 agents for the whole
// recurrence.  Wave w owns units [32w,32w+32) (gate B-frags in 96 VGPRs).
// h is parity double-buffered (kills A<->B WAR); each wave computes its OWN
// x copy (+2 MFMA) so the x feedback is in-wave -> ONE barrier per step:
//   [A gates 24 MFMA + B act 8 cells + h-write PN]  -- barrier --
//   [C: ah reads h_PN; wave0: rel(2 MFMA)+predh, both: x(2 MFMA)+own-x-write]
// z row stride 184 halves (<=2-way banks): [x_w0 16 | x_w1 16 | zeros 16 |
// h_par0 64 | h_par1 64 | pad 8].  pred stays in LDS, single coalesced
// float4 flush (the R5 RMW disaster reverts).
__global__ __launch_bounds__(128, 2) void lstm_kernel(
    const void* __restrict__ traj_rel,
    const void* __restrict__ h0,
    const void* __restrict__ c0,
    const float* __restrict__ ws,
    float* __restrict__ out)
{
    __shared__ _Float16 zsh[16 * 184];       // 5888 B
    __shared__ _Float16 predh[12 * 30 * 18]; // 12960 B

    const int tid = threadIdx.x;
    const int lane = tid & 63;
    const int w = __builtin_amdgcn_readfirstlane(tid >> 6);  // wave 0/1
    const int col16 = lane & 15;
    const int q4 = lane >> 4;            // 0..3
    const int gbase = blockIdx.x * 16;
    const int isf32 = ((const int*)(ws + FLAG_IDX))[0];

    // ---- per-lane constants ----
    const float4v* wfg = (const float4v*)ws;
    half8 Bf[2][4][3];
#pragma unroll
    for (int ug = 0; ug < 2; ++ug)
#pragma unroll
        for (int g = 0; g < 4; ++g)
#pragma unroll
            for (int ks = 0; ks < 3; ++ks)
                Bf[ug][g][ks] = __builtin_bit_cast(half8,
                    wfg[(((w * 2 + ug) * 4 + g) * 3 + ks) * 64 + lane]);
    float bias8[8];
#pragma unroll
    for (int ug = 0; ug < 2; ++ug)
#pragma unroll
        for (int g = 0; g < 4; ++g)
            bias8[ug * 4 + g] = ws[BIASB_OFF + g * 64 + w * 32 + ug * 16 + col16];
    half8 wfcR[2], wfcX[2];
    {
        const float4v* wcg = (const float4v*)(ws + WCF_OFF);
#pragma unroll
        for (int ks = 0; ks < 2; ++ks) {
            wfcR[ks] = __builtin_bit_cast(half8, wcg[ks * 64 + lane]);
            wfcX[ks] = __builtin_bit_cast(half8, wcg[(2 + ks) * 64 + lane]);
        }
    }
    const float cbr = ws[CBIAS_OFF + col16];
    const float cbx = ws[CBIAS_OFF + 16 + col16];

    // ---- c state: 8 cells/lane (agent q4*4+i, unit w*32+ug*16+col16) ----
    float c[8];
#pragma unroll
    for (int ug = 0; ug < 2; ++ug)
#pragma unroll
        for (int i = 0; i < 4; ++i)
            c[ug * 4 + i] = ldin(c0, (gbase + q4 * 4 + i) * 64
                                     + w * 32 + ug * 16 + col16, isf32);

    // ---- init z: h0 -> par0, x0 (both copies), zeros, pad ----
    {
        int m = tid & 15, jq3 = tid >> 4;   // agent, octile 0..7
        _Float16* zr = &zsh[m * 184];
        half8 ha;
#pragma unroll
        for (int i = 0; i < 8; ++i)
            ha[i] = (_Float16)ldin(h0, (gbase + m) * 64 + jq3 * 8 + i, isf32);
        *(half8*)&zr[48 + jq3 * 8] = ha;
        if (jq3 < 2) {
            float rx = ldin(traj_rel, 2 * (gbase + m), isf32);
            float ry = ldin(traj_rel, 2 * (gbase + m) + 1, isf32);
            half8 xs;
#pragma unroll
            for (int i = 0; i < 8; ++i) {
                int e = jq3 * 8 + i;
                float x = fmaf(rx, ws[SXY_OFF + e * 3],
                          fmaf(ry, ws[SXY_OFF + e * 3 + 1], ws[SXY_OFF + e * 3 + 2]));
                xs[i] = (_Float16)(x > 0.f ? x : 0.01f * x);
            }
            *(half8*)&zr[jq3 * 8] = xs;        // x copy wave0
            *(half8*)&zr[16 + jq3 * 8] = xs;   // x copy wave1
        } else if (jq3 == 2) {   // zeros k=80..95
            half8 zz = {};
            *(half8*)&zr[32] = zz;
            *(half8*)&zr[40] = zz;
        } else if (jq3 == 3) {   // stride pad
            half8 zz = {};
            *(half8*)&zr[176] = zz;
        }
    }
    __syncthreads();

    // ---- precomputed addresses (halves) ----
    const int zrow = col16 * 184;
    int azb[2][3];
#pragma unroll
    for (int p = 0; p < 2; ++p) {
        azb[p][0] = zrow + ((q4 < 2) ? (w * 16 + q4 * 8)
                                     : (48 + p * 64 + (q4 - 2) * 8));
        azb[p][1] = zrow + 48 + p * 64 + (q4 + 2) * 8;
        azb[p][2] = zrow + ((q4 < 2) ? (48 + p * 64 + (q4 + 6) * 8)
                                     : (32 + (q4 - 2) * 8));
    }
    const int ahb = zrow + 48 + q4 * 8;              // + PN*64 (+32)
    const int hwb = 48 + w * 32 + col16;             // + PN*64 + ug*16 + row*184
    const int xwb = w * 16 + col16;                  // + row*184

#define STEP(PC, PN, T, LAST) do {                                            \
    half8 az0 = *(const half8*)&zsh[azb[PC][0]];                              \
    half8 az1 = *(const half8*)&zsh[azb[PC][1]];                              \
    half8 az2 = *(const half8*)&zsh[azb[PC][2]];                              \
    _Pragma("unroll")                                                         \
    for (int ug = 0; ug < 2; ++ug) {                                          \
        float4v acc[4];                                                       \
        _Pragma("unroll")                                                     \
        for (int g = 0; g < 4; ++g) {                                         \
            float bv = bias8[ug * 4 + g];                                     \
            acc[g][0] = bv; acc[g][1] = bv; acc[g][2] = bv; acc[g][3] = bv;   \
        }                                                                     \
        _Pragma("unroll")                                                     \
        for (int g = 0; g < 4; ++g) {                                         \
            acc[g] = __builtin_amdgcn_mfma_f32_16x16x32_f16(                  \
                az0, Bf[ug][g][0], acc[g], 0, 0, 0);                          \
            acc[g] = __builtin_amdgcn_mfma_f32_16x16x32_f16(                  \
                az1, Bf[ug][g][1], acc[g], 0, 0, 0);                          \
            acc[g] = __builtin_amdgcn_mfma_f32_16x16x32_f16(                  \
                az2, Bf[ug][g][2], acc[g], 0, 0, 0);                          \
        }                                                                     \
        _Pragma("unroll")                                                     \
        for (int i = 0; i < 4; ++i) {                                         \
            float ei = FEXP2(acc[0][i]);                                      \
            float ef = FEXP2(acc[1][i]);                                      \
            float eg = FEXP2(acc[2][i]);                                      \
            float eo = FEXP2(acc[3][i]);                                      \
            float pp = (1.f + ei) * (1.f + eg);                               \
            float qq = 1.f + ef;                                              \
            float cn = fmaf(c[ug * 4 + i], pp, (1.f - eg) * qq) * FRCP(pp * qq);\
            c[ug * 4 + i] = cn;                                               \
            float ec = FEXP2(cn * N2LOG2E);                                   \
            float hn = (1.f - ec) * FRCP((1.f + eo) * (1.f + ec));            \
            zsh[(q4 * 4 + i) * 184 + hwb + (PN) * 64 + ug * 16] = (_Float16)hn;\
        }                                                                     \
    }                                                                         \
    __syncthreads();                                                          \
    half8 ah0 = *(const half8*)&zsh[ahb + (PN) * 64];                         \
    half8 ah1 = *(const half8*)&zsh[ahb + (PN) * 64 + 32];                    \
    if (w == 0) {                                                             \
        float4v rr;                                                           \
        rr[0] = cbr; rr[1] = cbr; rr[2] = cbr; rr[3] = cbr;                   \
        rr = __builtin_amdgcn_mfma_f32_16x16x32_f16(ah0, wfcR[0], rr, 0, 0, 0);\
        rr = __builtin_amdgcn_mfma_f32_16x16x32_f16(ah1, wfcR[1], rr, 0, 0, 0);\
        if (col16 < 12) {                                                     \
            half4 hv;                                                         \
            _Pragma("unroll")                                                 \
            for (int i = 0; i < 4; ++i) hv[i] = (_Float16)rr[i];              \
            *(half4*)&predh[(col16 * 30 + (T)) * 18 + q4 * 4] = hv;           \
        }                                                                     \
    }                                                                         \
    if (!(LAST)) {                                                            \
        float4v rx;                                                           \
        rx[0] = cbx; rx[1] = cbx; rx[2] = cbx; rx[3] = cbx;                   \
        rx = __builtin_amdgcn_mfma_f32_16x16x32_f16(ah0, wfcX[0], rx, 0, 0, 0);\
        rx = __builtin_amdgcn_mfma_f32_16x16x32_f16(ah1, wfcX[1], rx, 0, 0, 0);\
        _Pragma("unroll")                                                     \
        for (int i = 0; i < 4; ++i) {                                         \
            float xv = rx[i];                                                 \
            xv = xv > 0.f ? xv : 0.01f * xv;                                  \
            zsh[(q4 * 4 + i) * 184 + xwb] = (_Float16)xv;                     \
        }                                                                     \
    }                                                                         \
} while (0)

    for (int t = 0; t < TT - 2; t += 2) {
        STEP(0, 1, t, 0);
        STEP(1, 0, t + 1, 0);
    }
    STEP(0, 1, TT - 2, 0);
    STEP(1, 0, TT - 1, 1);
    __syncthreads();   // predh complete (wave0) before team flush

    // ---- coalesced flush: predh -> out (1440 float4 / 128 thr) ----
    {
        float4* po4 = (float4*)(out + (size_t)gbase * 360);
#pragma unroll 1
        for (int q2 = 0; q2 < 12; ++q2) {
            int idx4 = q2 * 128 + tid;
            if (idx4 < 1440) {
                int a = idx4 / 90, rem = idx4 % 90;
                int m = rem / 15, tq = rem % 15;
                int t0 = tq * 2;
                float4 o;
                o.x = (float)predh[((2 * m + 0) * 30 + t0) * 18 + a];
                o.y = (float)predh[((2 * m + 1) * 30 + t0) * 18 + a];
                o.z = (float)predh[((2 * m + 0) * 30 + t0 + 1) * 18 + a];
                o.w = (float)predh[((2 * m + 1) * 30 + t0 + 1) * 18 + a];
                po4[idx4] = o;
            }
        }
    }

    // ---- conf = softmax(h_30 @ Wconf^T + bconf): wave w -> agents w*8.. ----
    // h_30 lives in parity 0 (t=29 wrote PN=0).
    {
        int r = w * 8 + (lane >> 3), qq = lane & 7;
        float l[6];
#pragma unroll
        for (int md = 0; md < 6; ++md)
            l[md] = (qq == 0) ? ws[BCONF_OFF + md] : 0.f;
#pragma unroll
        for (int jj = 0; jj < 8; ++jj) {
            float hv = (float)zsh[r * 184 + 48 + qq * 8 + jj];
#pragma unroll
            for (int md = 0; md < 6; ++md)
                l[md] = fmaf(hv, ws[WCONF_OFF + md * 64 + qq * 8 + jj], l[md]);
        }
#pragma unroll
        for (int md = 0; md < 6; ++md) {
            l[md] += __shfl_xor(l[md], 1);
            l[md] += __shfl_xor(l[md], 2);
            l[md] += __shfl_xor(l[md], 4);
        }
        if (qq == 0) {
            float mx = l[0];
#pragma unroll
            for (int md = 1; md < 6; ++md) mx = fmaxf(mx, l[md]);
            float ex[6], s = 0.f;
#pragma unroll
            for (int md = 0; md < 6; ++md) { ex[md] = __expf(l[md] - mx); s += ex[md]; }
            float inv = FRCP(s);
#pragma unroll
            for (int md = 0; md < 6; ++md)
                out[CONF_BASE + (size_t)(gbase + r) * 6 + md] = ex[md] * inv;
        }
    }
}

extern "C" void kernel_launch(void* const* d_in, const int* in_sizes, int n_in,
                              void* d_out, int out_size, void* d_ws, size_t ws_size,
                              hipStream_t stream) {
    const void* traj_rel = d_in[1];
    const void* h0   = d_in[2];
    const void* c0   = d_in[3];
    const void* W_ih = d_in[4];
    const void* W_hh = d_in[5];
    const void* b_ih = d_in[6];
    const void* b_hh = d_in[7];
    const void* W_se = d_in[8];
    const void* b_se = d_in[9];
    const void* W_pos  = d_in[10];
    const void* b_pos  = d_in[11];
    const void* W_conf = d_in[12];
    const void* b_conf = d_in[13];
    float* ws = (float*)d_ws;
    float* out = (float*)d_out;

    detect_kernel<<<1, 256, 0, stream>>>((const unsigned short*)W_hh,
                                         (int*)(ws + FLAG_IDX));
    prep_kernel<<<40, 256, 0, stream>>>(W_ih, W_hh, b_ih, b_hh, W_se, b_se,
                                        W_pos, b_pos, W_conf, b_conf, ws);
    lstm_kernel<<<BATCH / 16, 128, 0, stream>>>(traj_rel, h0, c0, ws, out);
}

// Round 7
// 197.873 us; speedup vs baseline: 2.0072x; 1.0373x over previous
//
#include <hip/hip_runtime.h>
#include <hip/hip_bf16.h>

typedef _Float16 half8 __attribute__((ext_vector_type(8)));
typedef _Float16 half4 __attribute__((ext_vector_type(4)));
typedef float float4v __attribute__((ext_vector_type(4)));

#define BATCH 32768
#define TT 30

#if __has_builtin(__builtin_amdgcn_exp2f)
#define FEXP2(x) __builtin_amdgcn_exp2f(x)
#else
#define FEXP2(x) __expf((x) * 0.6931471805599453f)
#endif
#if __has_builtin(__builtin_amdgcn_rcpf)
#define FRCP(x) __builtin_amdgcn_rcpf(x)
#else
#define FRCP(x) (1.0f / (x))
#endif

#define NLOG2E  -1.4426950408889634f
#define N2LOG2E -2.8853900817779268f

// ws offsets (floats). Gate weights PRESCALED (-log2e; gate g -2log2e).
// SWAPPED-OPERAND GEMMs: W frags are the A operand (row=lane&15=unit),
// z frags the B operand (col=lane&15=agent) -- identical per-lane data to
// the old roles, so prep layouts are unchanged.  D: lane holds 4 UNITS x
// 1 AGENT -> h/x/pred writes are contiguous half4 (b64), no scalar b16.
// Gate bias is folded into the K-pad column: z[k=80]=1.0, W[k=80]=bias.
#define WFRAG_OFF 0        // f16[4 wv][4 gate][3 ks][64 lane][8] = 24576 halves
#define WCF_OFF   12288    // f16[2 role][2 ks][64 lane][8] = 2048 halves
#define BIASB_OFF 13312    // f32[256]  (unused by lstm now; kept)
#define SXY_OFF   13568    // f32[16][3]   (Sx, Sy, bse)
#define CBIAS_OFF 13616    // f32[2][16]   (role0: bpos|0, role1: bx)
#define WCONF_OFF 13648    // f32[384]
#define BCONF_OFF 14032    // f32[6]
#define FLAG_IDX  14038    // int: 1 => inputs fp32, 0 => bf16
#define CONF_BASE (BATCH * 360)

__global__ void detect_kernel(const unsigned short* __restrict__ raw,
                              int* __restrict__ flag_out) {
    __shared__ int sflag[256];
    int local = 0;
    for (int i = threadIdx.x; i < 16384; i += 256) {
        unsigned short u = raw[i];
        if ((u & 0x7F80u) == 0x7F80u) local = 1;
    }
    sflag[threadIdx.x] = local;
    __syncthreads();
    if (threadIdx.x == 0) {
        int f = 0;
        for (int i = 0; i < 256; ++i) f |= sflag[i];
        flag_out[0] = f;
    }
}

__device__ __forceinline__ float ldin(const void* p, int i, int isf32) {
    return isf32 ? ((const float*)p)[i]
                 : (float)((const __hip_bfloat16*)p)[i];
}

__global__ void prep_kernel(const void* __restrict__ W_ih,
                            const void* __restrict__ W_hh,
                            const void* __restrict__ b_ih,
                            const void* __restrict__ b_hh,
                            const void* __restrict__ W_se,
                            const void* __restrict__ b_se,
                            const void* __restrict__ W_pos,
                            const void* __restrict__ b_pos,
                            const void* __restrict__ W_conf,
                            const void* __restrict__ b_conf,
                            float* __restrict__ ws)
{
    const int isf32 = ((const int*)(ws + FLAG_IDX))[0];
    int tid = blockIdx.x * blockDim.x + threadIdx.x;
    int stride = gridDim.x * blockDim.x;
    _Float16* wfh = (_Float16*)ws;

    // Gate-GEMM W fragments, 16x16x32 tiles, K padded to 96.
    // k==80 carries the (prescaled) gate bias; z[k=80]=1 in the kernel.
    for (int idx = tid; idx < 24576; idx += stride) {
        int jj = idx & 7, r = idx >> 3;
        int lane = r & 63; r >>= 6;
        int ks = r % 3; r /= 3;
        int gate = r & 3; int wv = r >> 2;
        int col = lane & 15, akq = lane >> 4;
        int k = ks * 32 + akq * 8 + jj;
        int row = gate * 64 + wv * 16 + col;
        float v = 0.f;
        if (k < 16) v = ldin(W_ih, row * 16 + k, isf32);
        else if (k < 80) v = ldin(W_hh, row * 64 + (k - 16), isf32);
        else if (k == 80) v = ldin(b_ih, row, isf32) + ldin(b_hh, row, isf32);
        v *= (gate == 2) ? N2LOG2E : NLOG2E;
        wfh[idx] = (_Float16)v;
    }
    // Fused C-GEMM fragments: role0 = Wpos (rel), role1 = M=Wse*Wpos (x).
    _Float16* wch = (_Float16*)(ws + WCF_OFF);
    for (int idx = tid; idx < 2048; idx += stride) {
        int jj = idx & 7, r = idx >> 3;
        int lane = r & 63; r >>= 6;
        int ks = r & 1, role = r >> 1;
        int col = lane & 15, akq = lane >> 4;
        int k = ks * 32 + akq * 8 + jj;   // 0..63 over h
        float v = 0.f;
        if (role == 0) {
            if (col < 12) v = ldin(W_pos, col * 64 + k, isf32);
        } else {
            float s = 0.f;
            for (int p = 0; p < 12; ++p)
                s += ldin(W_se, col * 12 + p, isf32) * ldin(W_pos, p * 64 + k, isf32);
            v = s;
        }
        wch[idx] = (_Float16)v;
    }
    for (int idx = tid; idx < 256; idx += stride) {
        int gate = idx >> 6;
        float scale = (gate == 2) ? N2LOG2E : NLOG2E;
        ws[BIASB_OFF + idx] = (ldin(b_ih, idx, isf32) + ldin(b_hh, idx, isf32)) * scale;
    }
    for (int idx = tid; idx < 16; idx += stride) {
        float sx = 0.f, sy = 0.f;
        for (int m = 0; m < 6; ++m) {
            sx += ldin(W_se, idx * 12 + 2 * m, isf32);
            sy += ldin(W_se, idx * 12 + 2 * m + 1, isf32);
        }
        ws[SXY_OFF + idx * 3 + 0] = sx;
        ws[SXY_OFF + idx * 3 + 1] = sy;
        ws[SXY_OFF + idx * 3 + 2] = ldin(b_se, idx, isf32);
    }
    for (int idx = tid; idx < 32; idx += stride) {
        int w = idx >> 4, cc = idx & 15;
        float v = 0.f;
        if (w == 0) {
            if (cc < 12) v = ldin(b_pos, cc, isf32);
        } else {
            float s = ldin(b_se, cc, isf32);
            for (int p = 0; p < 12; ++p)
                s += ldin(W_se, cc * 12 + p, isf32) * ldin(b_pos, p, isf32);
            v = s;
        }
        ws[CBIAS_OFF + idx] = v;
    }
    for (int idx = tid; idx < 384; idx += stride)
        ws[WCONF_OFF + idx] = ldin(W_conf, idx, isf32);
    for (int idx = tid; idx < 6; idx += stride)
        ws[BCONF_OFF + idx] = ldin(b_conf, idx, isf32);
}

// block = 256 thr (4 waves), 32 agents in two 16-agent groups, h parity
// double-buffered, 2 barriers/step (R4 schedule, unchanged):
//   S1: A+B(G0,t) all waves | C(G1,t-1) waves 2,3      -- bar
//   S2: A+B(G1,t) all waves | C(G0,t)   waves 0,1      -- bar
// SWAPPED operands: mfma(Wfrag, zfrag) -> lane holds 4 units x 1 agent
// (agent = col16, units = wid*16 + akq*4 + i) -> h-write is ONE b64 per
// phase, x-write ONE b64, killing the 12 scalar b16 writes/wave-step and
// their bank conflicts.  Gate bias rides the k=80 column (z[k80]=1).
// z row layout per group (stride 168 halves):
//   [x 0..15 | k-pad 16..31 (16 -> 1.0) | h_par0 32..95 | h_par1 96..159]
__global__ __launch_bounds__(256, 4) void lstm_kernel(
    const void* __restrict__ traj_rel,
    const void* __restrict__ h0,
    const void* __restrict__ c0,
    const float* __restrict__ ws,
    float* __restrict__ out)
{
    __shared__ _Float16 zsh[2 * 16 * 168];
    __shared__ _Float16 predh[32 * 30 * 12];   // [agent][t][p]

    const int tid = threadIdx.x;
    const int lane = tid & 63;
    const int wid = __builtin_amdgcn_readfirstlane(tid >> 6);  // wave id 0..3
    const int role = wid & 1;           // C-phase role: 0=rel, 1=x
    const int col16 = lane & 15;        // agent (D col)
    const int akq = lane >> 4;          // 0..3 (D row quarter)
    const int base = blockIdx.x * 32;
    const int isf32 = ((const int*)(ws + FLAG_IDX))[0];

    // ---- per-lane constants ----
    const float4v* wfg = (const float4v*)ws;
    half8 Bf[4][3];
#pragma unroll
    for (int tl = 0; tl < 4; ++tl)
#pragma unroll
        for (int ks = 0; ks < 3; ++ks)
            Bf[tl][ks] = __builtin_bit_cast(half8,
                wfg[((wid * 4 + tl) * 3 + ks) * 64 + lane]);
    half8 wfc[2];
    {
        const float4v* wcg = (const float4v*)(ws + WCF_OFF);
#pragma unroll
        for (int ks = 0; ks < 2; ++ks)
            wfc[ks] = __builtin_bit_cast(half8, wcg[(role * 2 + ks) * 64 + lane]);
    }
    const float4v cb4 = *(const float4v*)&ws[CBIAS_OFF + role * 16 + akq * 4];

    // ---- c state: cell (agent col16, unit wid*16 + akq*4 + i) ----
    float cg0[4], cg1[4];
#pragma unroll
    for (int i = 0; i < 4; ++i) {
        int unit = wid * 16 + akq * 4 + i;
        cg0[i] = ldin(c0, (base + col16) * 64 + unit, isf32);
        cg1[i] = ldin(c0, (base + 16 + col16) * 64 + unit, isf32);
    }
    // ---- init z: h0 -> par0, x0, k-pad (1.0 at k=80) ----
    {
        int m = tid & 31, jq2 = tid >> 5;   // agent-in-block, octile 0..7
        int g = m >> 4, row = m & 15;
        _Float16* zr = &zsh[g * 2688 + row * 168];
        half8 ha;
#pragma unroll
        for (int i = 0; i < 8; ++i)
            ha[i] = (_Float16)ldin(h0, (base + m) * 64 + jq2 * 8 + i, isf32);
        *(half8*)&zr[32 + jq2 * 8] = ha;
        if (jq2 < 4) {
            float rx = ldin(traj_rel, 2 * (base + m), isf32);
            float ry = ldin(traj_rel, 2 * (base + m) + 1, isf32);
            half4 xs;
#pragma unroll
            for (int i = 0; i < 4; ++i) {
                int e = 4 * jq2 + i;
                float x = fmaf(rx, ws[SXY_OFF + e * 3],
                          fmaf(ry, ws[SXY_OFF + e * 3 + 1], ws[SXY_OFF + e * 3 + 2]));
                xs[i] = (_Float16)(x > 0.f ? x : 0.01f * x);
            }
            *(half4*)&zr[4 * jq2] = xs;
        } else if (jq2 == 4) {   // k = 80..87: bias column (k80 = 1.0)
            half8 zz = {};
            zz[0] = (_Float16)1.0f;
            *(half8*)&zr[16] = zz;
        } else if (jq2 == 5) {   // k = 88..95: zeros
            half8 zz = {};
            *(half8*)&zr[24] = zz;
        }
    }
    __syncthreads();

    // ---- precomputed LDS addresses (halves) ----
    int aoff[2][3];   // z B-frag base per parity per ks (chunk-mapped)
#pragma unroll
    for (int p = 0; p < 2; ++p)
#pragma unroll
        for (int ks = 0; ks < 3; ++ks) {
            int q = ks * 4 + akq;          // global k-chunk 0..11
            int off = (q < 2) ? q * 8
                    : (q < 10) ? 32 + p * 64 + (q - 2) * 8
                               : 16 + (q - 10) * 8;
            aoff[p][ks] = col16 * 168 + off;
        }
    const int zcb = col16 * 168 + 32 + akq * 8;      // C h-read (+P*64 +ks*32)
    const int hw4 = col16 * 168 + 32 + wid * 16 + akq * 4;  // h-write (+PN*64)
    const int xw4 = col16 * 168 + akq * 4;           // x-write

#define ZG(g) (&zsh[(g) * 2688])

#define PHASE_AB(ZG_, PC, PN, CARR) do {                                      \
    float4v acc_[4];                                                          \
    _Pragma("unroll")                                                         \
    for (int g = 0; g < 4; ++g) {                                             \
        acc_[g][0] = 0.f; acc_[g][1] = 0.f; acc_[g][2] = 0.f; acc_[g][3] = 0.f;\
    }                                                                         \
    _Pragma("unroll")                                                         \
    for (int ks = 0; ks < 3; ++ks) {                                          \
        half8 af_ = *(const half8*)&(ZG_)[aoff[PC][ks]];                      \
        _Pragma("unroll")                                                     \
        for (int g = 0; g < 4; ++g)                                           \
            acc_[g] = __builtin_amdgcn_mfma_f32_16x16x32_f16(                 \
                Bf[g][ks], af_, acc_[g], 0, 0, 0);                            \
    }                                                                         \
    half4 hv_;                                                                \
    _Pragma("unroll")                                                         \
    for (int i = 0; i < 4; ++i) {                                             \
        float ei = FEXP2(acc_[0][i]);                                         \
        float ef = FEXP2(acc_[1][i]);                                         \
        float eg = FEXP2(acc_[2][i]);                                         \
        float eo = FEXP2(acc_[3][i]);                                         \
        float pp = (1.f + ei) * (1.f + eg);                                   \
        float qq = 1.f + ef;                                                  \
        float cn = fmaf((CARR)[i], pp, (1.f - eg) * qq) * FRCP(pp * qq);      \
        (CARR)[i] = cn;                                                       \
        float ec = FEXP2(cn * N2LOG2E);                                       \
        float hn = (1.f - ec) * FRCP((1.f + eo) * (1.f + ec));                \
        hv_[i] = (_Float16)hn;                                                \
    }                                                                         \
    *(half4*)&(ZG_)[hw4 + (PN) * 64] = hv_;                                   \
} while (0)

#define PHASE_C(ZG_, P, T, GI) do {                                           \
    float4v racc_;                                                            \
    racc_[0] = cb4[0]; racc_[1] = cb4[1]; racc_[2] = cb4[2]; racc_[3] = cb4[3];\
    _Pragma("unroll")                                                         \
    for (int ks = 0; ks < 2; ++ks) {                                          \
        half8 af_ = *(const half8*)&(ZG_)[zcb + (P) * 64 + ks * 32];          \
        racc_ = __builtin_amdgcn_mfma_f32_16x16x32_f16(                       \
            wfc[ks], af_, racc_, 0, 0, 0);                                    \
    }                                                                         \
    if (role == 0) {                                                          \
        if (akq < 3) {                                                        \
            half4 pv_;                                                        \
            _Pragma("unroll")                                                 \
            for (int i = 0; i < 4; ++i) pv_[i] = (_Float16)racc_[i];          \
            *(half4*)&predh[(((GI) * 16 + col16) * 30 + (T)) * 12 + akq * 4] = pv_;\
        }                                                                     \
    } else if ((T) != TT - 1) {                                               \
        half4 xv4_;                                                           \
        _Pragma("unroll")                                                     \
        for (int i = 0; i < 4; ++i) {                                         \
            float xv_ = racc_[i];                                             \
            xv4_[i] = (_Float16)(xv_ > 0.f ? xv_ : 0.01f * xv_);              \
        }                                                                     \
        *(half4*)&(ZG_)[xw4] = xv4_;                                          \
    }                                                                         \
} while (0)

    _Float16* const zg0p = ZG(0);
    _Float16* const zg1p = ZG(1);

    // ---- prologue: t = 0 (parity: read 0, write 1) ----
    PHASE_AB(zg0p, 0, 1, cg0);                       // S1_0
    __syncthreads();
    PHASE_AB(zg1p, 0, 1, cg1);
    if (wid < 2) PHASE_C(zg0p, 1, 0, 0);             // S2_0
    __syncthreads();

    // ---- main loop, 2 steps per iteration (compile-time parity) ----
    for (int t = 1; t < TT - 1; t += 2) {
        // step t (odd): pc=1, pn=0
        PHASE_AB(zg0p, 1, 0, cg0);
        if (wid >= 2) PHASE_C(zg1p, 1, t - 1, 1);    // S1
        __syncthreads();
        PHASE_AB(zg1p, 1, 0, cg1);
        if (wid < 2) PHASE_C(zg0p, 0, t, 0);         // S2
        __syncthreads();
        // step t+1 (even): pc=0, pn=1
        PHASE_AB(zg0p, 0, 1, cg0);
        if (wid >= 2) PHASE_C(zg1p, 0, t, 1);        // S1
        __syncthreads();
        PHASE_AB(zg1p, 0, 1, cg1);
        if (wid < 2) PHASE_C(zg0p, 1, t + 1, 0);     // S2
        __syncthreads();
    }
    // ---- tail: t = 29 (odd) ----
    PHASE_AB(zg0p, 1, 0, cg0);
    if (wid >= 2) PHASE_C(zg1p, 1, TT - 2, 1);       // S1: C(G1,28)
    __syncthreads();
    PHASE_AB(zg1p, 1, 0, cg1);
    if (wid < 2) PHASE_C(zg0p, 0, TT - 1, 0);        // S2: C(G0,29)
    __syncthreads();
    if (wid >= 2) PHASE_C(zg1p, 0, TT - 1, 1);       // epilogue: C(G1,29)
    __syncthreads();

    // ---- coalesced flush: predh[a][t][p] -> out (float4 per thread-iter) ----
    {
        float4* po4 = (float4*)(out + (size_t)base * 360);
#pragma unroll 1
        for (int q2 = 0; q2 < 12; ++q2) {
            int idx4 = q2 * 256 + tid;
            if (idx4 < 2880) {
                int a = idx4 / 90, rem = idx4 % 90;
                int m = rem / 15, tq = rem % 15;
                int t0 = tq * 2;
                float4 o;
                o.x = (float)predh[(a * 30 + t0) * 12 + 2 * m];
                o.y = (float)predh[(a * 30 + t0) * 12 + 2 * m + 1];
                o.z = (float)predh[(a * 30 + t0 + 1) * 12 + 2 * m];
                o.w = (float)predh[(a * 30 + t0 + 1) * 12 + 2 * m + 1];
                po4[idx4] = o;
            }
        }
    }

    // ---- conf = softmax(h_30 @ Wconf^T + bconf): wave 0, lanes 0..31 ----
    // h_30 lives in parity 0 (t=29 wrote PN=0), offset 32.
    if (wid == 0 && lane < 32) {
        int m = lane;
        int g = m >> 4, row = m & 15;
        float l[6];
#pragma unroll
        for (int md = 0; md < 6; ++md) l[md] = ws[BCONF_OFF + md];
        for (int jj = 0; jj < 64; ++jj) {
            float hv = (float)zsh[g * 2688 + row * 168 + 32 + jj];
#pragma unroll
            for (int md = 0; md < 6; ++md)
                l[md] = fmaf(hv, ws[WCONF_OFF + md * 64 + jj], l[md]);
        }
        float mx = l[0];
#pragma unroll
        for (int md = 1; md < 6; ++md) mx = fmaxf(mx, l[md]);
        float ex[6], s = 0.f;
#pragma unroll
        for (int md = 0; md < 6; ++md) { ex[md] = __expf(l[md] - mx); s += ex[md]; }
        float inv = FRCP(s);
#pragma unroll
        for (int md = 0; md < 6; ++md)
            out[CONF_BASE + (size_t)(base + m) * 6 + md] = ex[md] * inv;
    }
}

extern "C" void kernel_launch(void* const* d_in, const int* in_sizes, int n_in,
                              void* d_out, int out_size, void* d_ws, size_t ws_size,
                              hipStream_t stream) {
    const void* traj_rel = d_in[1];
    const void* h0   = d_in[2];
    const void* c0   = d_in[3];
    const void* W_ih = d_in[4];
    const void* W_hh = d_in[5];
    const void* b_ih = d_in[6];
    const void* b_hh = d_in[7];
    const void* W_se = d_in[8];
    const void* b_se = d_in[9];
    const void* W_pos  = d_in[10];
    const void* b_pos  = d_in[11];
    const void* W_conf = d_in[12];
    const void* b_conf = d_in[13];
    float* ws = (float*)d_ws;
    float* out = (float*)d_out;

    detect_kernel<<<1, 256, 0, stream>>>((const unsigned short*)W_hh,
                                         (int*)(ws + FLAG_IDX));
    prep_kernel<<<40, 256, 0, stream>>>(W_ih, W_hh, b_ih, b_hh, W_se, b_se,
                                        W_pos, b_pos, W_conf, b_conf, ws);
    lstm_kernel<<<BATCH / 32, 256, 0, stream>>>(traj_rel, h0, c0, ws, out);
}